// Round 6
// baseline (116.504 us; speedup 1.0000x reference)
//
#include <hip/hip_runtime.h>

// SpatialLocalSum: out[b,hw,s] = log( sum_c exp(x[b,hw,c]) * acc[hw,c,s] ) - log(sum_c acc[hw,c,s])
// (reference's mx/mw stabilizers cancel algebraically; exp(x) safe for x~N(0,1))
//
// DIAGNOSTIC ROUND: identical kernel launched TWICE (idempotent — second pass
// recomputes/rewrites the same output). dur_us(R6) - dur_us(R5) isolates one
// warm kernel pass, distinguishing "kernel ~33us, pattern-bound" from
// "kernel ~15us, harness-overhead-dominated" — our dispatch is invisible in
// the top-5 profile table (all fills >= 41.5us), so this is the only way
// to measure it.

typedef __attribute__((ext_vector_type(8))) short s8v;   // 8 bf16 (A/B fragment)
typedef __attribute__((ext_vector_type(4))) float f4v;   // 4 fp32 (native vec: nontemporal-OK)

__device__ __forceinline__ unsigned short f2bf(float f) {
    unsigned int u = __float_as_uint(f);
    u += 0x7FFFu + ((u >> 16) & 1u);   // round-to-nearest-even
    return (unsigned short)(u >> 16);
}

__global__ __launch_bounds__(256) void sls_kernel(
    const float* __restrict__ x,     // [128,1024,64]
    const float* __restrict__ acc,   // [1024,64,64]  (c,s) per hw
    float* __restrict__ out)         // [128,1024,64]
{
    const int hw   = blockIdx.x;
    const int t    = threadIdx.x;
    const int lane = t & 63;
    const int quad = lane >> 4;
    const int nn   = lane & 15;
    const int wave = t >> 6;

    // e (bf16) row-major, stride 72 elems (144B): b128-aligned frag reads, ~2-way max.
    __shared__ unsigned short e_lds[2][64 * 72];   // 18.4 KB, one buffer per b-half

    const int r0 = t >> 4;           // 0..15
    const int c0 = (t & 15) * 4;     // 0..60
    const float* xbase = x + (size_t)hw * 64 + c0;

    // ---- issue ALL global loads up front: x half0, acc, x half1 ----
    f4v xv0[4], xv1[4];
    #pragma unroll
    for (int it = 0; it < 4; ++it)
        xv0[it] = __builtin_nontemporal_load((const f4v*)(xbase + (size_t)(r0 + 16 * it) * 65536));

    const int ni = wave;             // s-tile per wave
    const float* accb = acc + (size_t)hw * 4096 + ni * 16 + nn;
    float bv[2][8];
    #pragma unroll
    for (int ks = 0; ks < 2; ++ks)
        #pragma unroll
        for (int j = 0; j < 8; ++j)
            bv[ks][j] = accb[(ks * 32 + quad * 8 + j) * 64];

    #pragma unroll
    for (int it = 0; it < 4; ++it)
        xv1[it] = __builtin_nontemporal_load((const f4v*)(xbase + (size_t)(64 + r0 + 16 * it) * 65536));

    // ---- half 0: e = bf16(exp(x)) -> LDS buffer 0 ----
    #pragma unroll
    for (int it = 0; it < 4; ++it) {
        f4v v = xv0[it];
        const int row = r0 + 16 * it;
        ushort4 pk;
        pk.x = f2bf(__expf(v.x));
        pk.y = f2bf(__expf(v.y));
        pk.z = f2bf(__expf(v.z));
        pk.w = f2bf(__expf(v.w));
        *(ushort4*)&e_lds[0][row * 72 + c0] = pk;
    }

    // ---- column sums + B fragments (shared by both halves) ----
    float csum = 0.f;
    #pragma unroll
    for (int ks = 0; ks < 2; ++ks)
        #pragma unroll
        for (int j = 0; j < 8; ++j) csum += bv[ks][j];
    csum += __shfl_xor(csum, 16);
    csum += __shfl_xor(csum, 32);
    const float lsum_n = __logf(csum);

    s8v bf0, bf1;
    #pragma unroll
    for (int j = 0; j < 8; ++j) {
        bf0[j] = (short)f2bf(bv[0][j]);
        bf1[j] = (short)f2bf(bv[1][j]);
    }

    __syncthreads();

    // ---- half 0: MFMA + epilogue (x half1 loads still in flight) ----
    float* outp = out + (size_t)hw * 64 + ni * 16 + nn;
    #pragma unroll
    for (int mi = 0; mi < 4; ++mi) {
        const unsigned short* rowp = &e_lds[0][(mi * 16 + nn) * 72];
        s8v a0 = *(const s8v*)(rowp + quad * 8);
        s8v a1 = *(const s8v*)(rowp + 32 + quad * 8);
        f4v d = {0.f, 0.f, 0.f, 0.f};
        d = __builtin_amdgcn_mfma_f32_16x16x32_bf16(a0, bf0, d, 0, 0, 0);
        d = __builtin_amdgcn_mfma_f32_16x16x32_bf16(a1, bf1, d, 0, 0, 0);
        #pragma unroll
        for (int r = 0; r < 4; ++r) {
            const int b_row = mi * 16 + quad * 4 + r;   // C/D: row=(lane>>4)*4+r, col=lane&15
            __builtin_nontemporal_store(__logf(d[r]) - lsum_n, outp + (size_t)b_row * 65536);
        }
    }

    // ---- half 1: e -> LDS buffer 1 (no WAR hazard: different buffer) ----
    #pragma unroll
    for (int it = 0; it < 4; ++it) {
        f4v v = xv1[it];
        const int row = r0 + 16 * it;
        ushort4 pk;
        pk.x = f2bf(__expf(v.x));
        pk.y = f2bf(__expf(v.y));
        pk.z = f2bf(__expf(v.z));
        pk.w = f2bf(__expf(v.w));
        *(ushort4*)&e_lds[1][row * 72 + c0] = pk;
    }
    __syncthreads();

    // ---- half 1: MFMA + epilogue ----
    #pragma unroll
    for (int mi = 0; mi < 4; ++mi) {
        const unsigned short* rowp = &e_lds[1][(mi * 16 + nn) * 72];
        s8v a0 = *(const s8v*)(rowp + quad * 8);
        s8v a1 = *(const s8v*)(rowp + 32 + quad * 8);
        f4v d = {0.f, 0.f, 0.f, 0.f};
        d = __builtin_amdgcn_mfma_f32_16x16x32_bf16(a0, bf0, d, 0, 0, 0);
        d = __builtin_amdgcn_mfma_f32_16x16x32_bf16(a1, bf1, d, 0, 0, 0);
        #pragma unroll
        for (int r = 0; r < 4; ++r) {
            const int b_row = 64 + mi * 16 + quad * 4 + r;
            __builtin_nontemporal_store(__logf(d[r]) - lsum_n, outp + (size_t)b_row * 65536);
        }
    }
}

extern "C" void kernel_launch(void* const* d_in, const int* in_sizes, int n_in,
                              void* d_out, int out_size, void* d_ws, size_t ws_size,
                              hipStream_t stream) {
    const float* x   = (const float*)d_in[0];
    const float* acc = (const float*)d_in[1];
    float* out = (float*)d_out;
    (void)in_sizes; (void)n_in; (void)d_ws; (void)ws_size; (void)out_size;
    // DIAGNOSTIC: two identical, idempotent launches. Same work every call,
    // graph-capture safe. dur_delta vs single-launch round = one kernel pass.
    sls_kernel<<<dim3(1024), dim3(256), 0, stream>>>(x, acc, out);
    sls_kernel<<<dim3(1024), dim3(256), 0, stream>>>(x, acc, out);
}

// Round 7
// 95.776 us; speedup vs baseline: 1.2164x; 1.2164x over previous
//
#include <hip/hip_runtime.h>

// SpatialLocalSum: out[b,hw,s] = log( sum_c exp(x[b,hw,c]) * acc[hw,c,s] ) - log(sum_c acc[hw,c,s])
// (reference's mx/mw stabilizers cancel algebraically; exp(x) safe for x~N(0,1))
//
// Measured (R6 double-launch diagnostic): one kernel pass ~17.8us vs 13.3us
// compulsory-traffic floor (84 MB @ 6.3 TB/s); dur_us carries ~80us of fixed
// harness fill/restore overhead. Single launch restored here.
// One block per hw (grid 1024, 4 blocks/CU), 256 threads, two pipelined
// b-halves sharing one acc read. Plain loads (inputs are L2/L3-warm from the
// harness restore); nontemporal stores (out is pure streaming).

typedef __attribute__((ext_vector_type(8))) short s8v;   // 8 bf16 (A/B fragment)
typedef __attribute__((ext_vector_type(4))) float f4v;   // 4 fp32

__device__ __forceinline__ unsigned short f2bf(float f) {
    unsigned int u = __float_as_uint(f);
    u += 0x7FFFu + ((u >> 16) & 1u);   // round-to-nearest-even
    return (unsigned short)(u >> 16);
}

__global__ __launch_bounds__(256) void sls_kernel(
    const float* __restrict__ x,     // [128,1024,64]
    const float* __restrict__ acc,   // [1024,64,64]  (c,s) per hw
    float* __restrict__ out)         // [128,1024,64]
{
    const int hw   = blockIdx.x;
    const int t    = threadIdx.x;
    const int lane = t & 63;
    const int quad = lane >> 4;
    const int nn   = lane & 15;
    const int wave = t >> 6;

    // e (bf16) row-major, stride 72 elems (144B): b128-aligned frag reads, ~2-way max.
    __shared__ unsigned short e_lds[2][64 * 72];   // 18.4 KB, one buffer per b-half

    const int r0 = t >> 4;           // 0..15
    const int c0 = (t & 15) * 4;     // 0..60
    const float* xbase = x + (size_t)hw * 64 + c0;

    // ---- issue ALL global loads up front: x half0, acc, x half1 ----
    f4v xv0[4], xv1[4];
    #pragma unroll
    for (int it = 0; it < 4; ++it)
        xv0[it] = *(const f4v*)(xbase + (size_t)(r0 + 16 * it) * 65536);

    const int ni = wave;             // s-tile per wave
    const float* accb = acc + (size_t)hw * 4096 + ni * 16 + nn;
    float bv[2][8];
    #pragma unroll
    for (int ks = 0; ks < 2; ++ks)
        #pragma unroll
        for (int j = 0; j < 8; ++j)
            bv[ks][j] = accb[(ks * 32 + quad * 8 + j) * 64];

    #pragma unroll
    for (int it = 0; it < 4; ++it)
        xv1[it] = *(const f4v*)(xbase + (size_t)(64 + r0 + 16 * it) * 65536);

    // ---- half 0: e = bf16(exp(x)) -> LDS buffer 0 ----
    #pragma unroll
    for (int it = 0; it < 4; ++it) {
        f4v v = xv0[it];
        const int row = r0 + 16 * it;
        ushort4 pk;
        pk.x = f2bf(__expf(v.x));
        pk.y = f2bf(__expf(v.y));
        pk.z = f2bf(__expf(v.z));
        pk.w = f2bf(__expf(v.w));
        *(ushort4*)&e_lds[0][row * 72 + c0] = pk;
    }

    // ---- column sums + B fragments (shared by both halves) ----
    float csum = 0.f;
    #pragma unroll
    for (int ks = 0; ks < 2; ++ks)
        #pragma unroll
        for (int j = 0; j < 8; ++j) csum += bv[ks][j];
    csum += __shfl_xor(csum, 16);
    csum += __shfl_xor(csum, 32);
    const float lsum_n = __logf(csum);

    s8v bf0, bf1;
    #pragma unroll
    for (int j = 0; j < 8; ++j) {
        bf0[j] = (short)f2bf(bv[0][j]);
        bf1[j] = (short)f2bf(bv[1][j]);
    }

    __syncthreads();

    // ---- half 0: MFMA + epilogue (x half1 loads still in flight) ----
    float* outp = out + (size_t)hw * 64 + ni * 16 + nn;
    #pragma unroll
    for (int mi = 0; mi < 4; ++mi) {
        const unsigned short* rowp = &e_lds[0][(mi * 16 + nn) * 72];
        s8v a0 = *(const s8v*)(rowp + quad * 8);
        s8v a1 = *(const s8v*)(rowp + 32 + quad * 8);
        f4v d = {0.f, 0.f, 0.f, 0.f};
        d = __builtin_amdgcn_mfma_f32_16x16x32_bf16(a0, bf0, d, 0, 0, 0);
        d = __builtin_amdgcn_mfma_f32_16x16x32_bf16(a1, bf1, d, 0, 0, 0);
        #pragma unroll
        for (int r = 0; r < 4; ++r) {
            const int b_row = mi * 16 + quad * 4 + r;   // C/D: row=(lane>>4)*4+r, col=lane&15
            __builtin_nontemporal_store(__logf(d[r]) - lsum_n, outp + (size_t)b_row * 65536);
        }
    }

    // ---- half 1: e -> LDS buffer 1 (no WAR hazard: different buffer) ----
    #pragma unroll
    for (int it = 0; it < 4; ++it) {
        f4v v = xv1[it];
        const int row = r0 + 16 * it;
        ushort4 pk;
        pk.x = f2bf(__expf(v.x));
        pk.y = f2bf(__expf(v.y));
        pk.z = f2bf(__expf(v.z));
        pk.w = f2bf(__expf(v.w));
        *(ushort4*)&e_lds[1][row * 72 + c0] = pk;
    }
    __syncthreads();

    // ---- half 1: MFMA + epilogue ----
    #pragma unroll
    for (int mi = 0; mi < 4; ++mi) {
        const unsigned short* rowp = &e_lds[1][(mi * 16 + nn) * 72];
        s8v a0 = *(const s8v*)(rowp + quad * 8);
        s8v a1 = *(const s8v*)(rowp + 32 + quad * 8);
        f4v d = {0.f, 0.f, 0.f, 0.f};
        d = __builtin_amdgcn_mfma_f32_16x16x32_bf16(a0, bf0, d, 0, 0, 0);
        d = __builtin_amdgcn_mfma_f32_16x16x32_bf16(a1, bf1, d, 0, 0, 0);
        #pragma unroll
        for (int r = 0; r < 4; ++r) {
            const int b_row = 64 + mi * 16 + quad * 4 + r;
            __builtin_nontemporal_store(__logf(d[r]) - lsum_n, outp + (size_t)b_row * 65536);
        }
    }
}

extern "C" void kernel_launch(void* const* d_in, const int* in_sizes, int n_in,
                              void* d_out, int out_size, void* d_ws, size_t ws_size,
                              hipStream_t stream) {
    const float* x   = (const float*)d_in[0];
    const float* acc = (const float*)d_in[1];
    float* out = (float*)d_out;
    (void)in_sizes; (void)n_in; (void)d_ws; (void)ws_size; (void)out_size;
    sls_kernel<<<dim3(1024), dim3(256), 0, stream>>>(x, acc, out);
}